// Round 1
// baseline (291.835 us; speedup 1.0000x reference)
//
#include <hip/hip_runtime.h>

#define DIM  33
#define DIM2 1089      // 33*33
#define DIM3 35937     // 33*33*33
#define HW   2073600   // 1080*1920
#define NPIX 8294400   // 4*HW

// ---------------------------------------------------------------------------
// Pre-pass: transpose LUT from [c][b][g][r] (c stride DIM3) into channel-packed
// [b][g][r] -> float4 (r,g,b,pad). One aligned 16B entry per lattice corner so
// the main kernel fetches all 3 channels of a corner with one dwordx4.
// ---------------------------------------------------------------------------
__global__ __launch_bounds__(256) void pack_lut_kernel(
        const float* __restrict__ lut, float4* __restrict__ lut4) {
    int i = blockIdx.x * blockDim.x + threadIdx.x;
    if (i >= DIM3) return;
    lut4[i] = make_float4(lut[i], lut[i + DIM3], lut[i + 2 * DIM3], 0.0f);
}

__device__ __forceinline__ float4 lerp4(float4 a, float4 b, float t) {
    return make_float4(fmaf(t, b.x - a.x, a.x),
                       fmaf(t, b.y - a.y, a.y),
                       fmaf(t, b.z - a.z, a.z),
                       0.0f);
}

__device__ __forceinline__ void trilerp_packed(
        float r, float g, float b, const float4* __restrict__ lut4,
        float& o0, float& o1, float& o2) {
    float rs = fminf(fmaxf(r, 0.0f), 1.0f) * 32.0f;
    float gs = fminf(fmaxf(g, 0.0f), 1.0f) * 32.0f;
    float bs = fminf(fmaxf(b, 0.0f), 1.0f) * 32.0f;
    int ri = min((int)rs, 31);   // rs >= 0, (int) == floor
    int gi = min((int)gs, 31);
    int bi = min((int)bs, 31);
    float fr = rs - (float)ri;
    float fg = gs - (float)gi;
    float fb = bs - (float)bi;
    const float4* p = lut4 + (bi * DIM2 + gi * DIM + ri);
    float4 c000 = p[0];
    float4 c001 = p[1];
    float4 c010 = p[DIM];
    float4 c011 = p[DIM + 1];
    float4 c100 = p[DIM2];
    float4 c101 = p[DIM2 + 1];
    float4 c110 = p[DIM2 + DIM];
    float4 c111 = p[DIM2 + DIM + 1];
    float4 a0 = lerp4(lerp4(c000, c001, fr), lerp4(c010, c011, fr), fg);
    float4 a1 = lerp4(lerp4(c100, c101, fr), lerp4(c110, c111, fr), fg);
    float4 o  = lerp4(a0, a1, fb);
    o0 = o.x; o1 = o.y; o2 = o.z;
}

// Main kernel: 4 pixels per thread; float4 coalesced loads of the r/g/b planes,
// packed dwordx4 gathers from the repacked LUT, float4 coalesced stores.
__global__ __launch_bounds__(256) void lut_apply_packed(
        const float* __restrict__ x, const float4* __restrict__ lut4,
        float* __restrict__ out) {
    int i4 = blockIdx.x * blockDim.x + threadIdx.x;
    const int HW4 = HW / 4;
    if (i4 >= NPIX / 4) return;
    int n   = i4 / HW4;
    int rem = i4 - n * HW4;
    size_t base = (size_t)n * (size_t)(3 * HW) + (size_t)rem * 4;

    const float4 rv = *(const float4*)(x + base);
    const float4 gv = *(const float4*)(x + base + HW);
    const float4 bv = *(const float4*)(x + base + 2 * (size_t)HW);

    float ra[4] = {rv.x, rv.y, rv.z, rv.w};
    float ga[4] = {gv.x, gv.y, gv.z, gv.w};
    float ba[4] = {bv.x, bv.y, bv.z, bv.w};
    float oa[4], ob[4], oc[4];
#pragma unroll
    for (int k = 0; k < 4; ++k) {
        trilerp_packed(ra[k], ga[k], ba[k], lut4, oa[k], ob[k], oc[k]);
    }
    *(float4*)(out + base)                    = make_float4(oa[0], oa[1], oa[2], oa[3]);
    *(float4*)(out + base + HW)               = make_float4(ob[0], ob[1], ob[2], ob[3]);
    *(float4*)(out + base + 2 * (size_t)HW)   = make_float4(oc[0], oc[1], oc[2], oc[3]);
}

// Fallback (only if d_ws is too small for the packed LUT): gather directly from
// the original [c][b][g][r] layout with scalar loads. Correct, slower.
__global__ __launch_bounds__(256) void lut_apply_direct(
        const float* __restrict__ x, const float* __restrict__ lut,
        float* __restrict__ out) {
    int i4 = blockIdx.x * blockDim.x + threadIdx.x;
    const int HW4 = HW / 4;
    if (i4 >= NPIX / 4) return;
    int n   = i4 / HW4;
    int rem = i4 - n * HW4;
    size_t base = (size_t)n * (size_t)(3 * HW) + (size_t)rem * 4;

    const float4 rv = *(const float4*)(x + base);
    const float4 gv = *(const float4*)(x + base + HW);
    const float4 bv = *(const float4*)(x + base + 2 * (size_t)HW);
    float ra[4] = {rv.x, rv.y, rv.z, rv.w};
    float ga[4] = {gv.x, gv.y, gv.z, gv.w};
    float ba[4] = {bv.x, bv.y, bv.z, bv.w};
    float o[3][4];
#pragma unroll
    for (int k = 0; k < 4; ++k) {
        float rs = fminf(fmaxf(ra[k], 0.0f), 1.0f) * 32.0f;
        float gs = fminf(fmaxf(ga[k], 0.0f), 1.0f) * 32.0f;
        float bs = fminf(fmaxf(ba[k], 0.0f), 1.0f) * 32.0f;
        int ri = min((int)rs, 31);
        int gi = min((int)gs, 31);
        int bi = min((int)bs, 31);
        float fr = rs - (float)ri;
        float fg = gs - (float)gi;
        float fb = bs - (float)bi;
        int cbase = bi * DIM2 + gi * DIM + ri;
#pragma unroll
        for (int c = 0; c < 3; ++c) {
            const float* p = lut + c * DIM3 + cbase;
            float v000 = p[0],          v001 = p[1];
            float v010 = p[DIM],        v011 = p[DIM + 1];
            float v100 = p[DIM2],       v101 = p[DIM2 + 1];
            float v110 = p[DIM2 + DIM], v111 = p[DIM2 + DIM + 1];
            float a00 = fmaf(fr, v001 - v000, v000);
            float a01 = fmaf(fr, v011 - v010, v010);
            float a10 = fmaf(fr, v101 - v100, v100);
            float a11 = fmaf(fr, v111 - v110, v110);
            float b0  = fmaf(fg, a01 - a00, a00);
            float b1  = fmaf(fg, a11 - a10, a10);
            o[c][k]   = fmaf(fb, b1 - b0, b0);
        }
    }
    *(float4*)(out + base)                  = make_float4(o[0][0], o[0][1], o[0][2], o[0][3]);
    *(float4*)(out + base + HW)             = make_float4(o[1][0], o[1][1], o[1][2], o[1][3]);
    *(float4*)(out + base + 2 * (size_t)HW) = make_float4(o[2][0], o[2][1], o[2][2], o[2][3]);
}

extern "C" void kernel_launch(void* const* d_in, const int* in_sizes, int n_in,
                              void* d_out, int out_size, void* d_ws, size_t ws_size,
                              hipStream_t stream) {
    const float* x   = (const float*)d_in[0];
    const float* lut = (const float*)d_in[1];
    float* out = (float*)d_out;

    const int groups = NPIX / 4;           // 2,073,600 float4 pixel-groups
    const int blocks = (groups + 255) / 256;  // 8100

    if (ws_size >= (size_t)DIM3 * sizeof(float4)) {
        float4* lut4 = (float4*)d_ws;
        pack_lut_kernel<<<(DIM3 + 255) / 256, 256, 0, stream>>>(lut, lut4);
        lut_apply_packed<<<blocks, 256, 0, stream>>>(x, lut4, out);
    } else {
        lut_apply_direct<<<blocks, 256, 0, stream>>>(x, lut, out);
    }
}

// Round 3
// 225.773 us; speedup vs baseline: 1.2926x; 1.2926x over previous
//
#include <hip/hip_runtime.h>
#include <hip/hip_fp16.h>

#define DIM  33
#define DIM2 1089      // 33*33
#define DIM3 35937     // 33*33*33
#define HW   2073600   // 1080*1920
#define NPIX 8294400   // 4*HW

// Native vector type — required for __builtin_nontemporal_load/store
// (HIP's float4 is a class and is rejected by the builtin).
typedef float  vf4 __attribute__((ext_vector_type(4)));
typedef _Float16 vh8 __attribute__((ext_vector_type(8)));

// ---------------------------------------------------------------------------
// Pre-pass: expand LUT into one 64B cache-line entry per lattice cell:
// 8 corners x 3 channels in fp16 (48B used, 64B stride, 64B aligned).
// Corner order: h[((db*2+dg)*2+dr)*3 + ch].
// Main kernel then needs only 3 dwordx4 gathers per pixel, all in ONE line.
// ---------------------------------------------------------------------------
union F4H {
    vf4      f4;
    _Float16 h[8];
};

__global__ __launch_bounds__(256) void pack_lut8_kernel(
        const float* __restrict__ lut, vf4* __restrict__ lut8) {
    int i = blockIdx.x * blockDim.x + threadIdx.x;
    if (i >= DIM3) return;
    int b   = i / DIM2;
    int rem = i - b * DIM2;
    int g   = rem / DIM;
    int r   = rem - g * DIM;
    int b1 = min(b + 1, DIM - 1);
    int g1 = min(g + 1, DIM - 1);
    int r1 = min(r + 1, DIM - 1);

    _Float16 h[32];
#pragma unroll
    for (int db = 0; db < 2; ++db)
#pragma unroll
        for (int dg = 0; dg < 2; ++dg)
#pragma unroll
            for (int dr = 0; dr < 2; ++dr) {
                int bb = db ? b1 : b;
                int gg = dg ? g1 : g;
                int rr = dr ? r1 : r;
                int base = bb * DIM2 + gg * DIM + rr;
                int ci = ((db * 2 + dg) * 2 + dr) * 3;
                h[ci + 0] = (_Float16)lut[base];
                h[ci + 1] = (_Float16)lut[base + DIM3];
                h[ci + 2] = (_Float16)lut[base + 2 * DIM3];
            }
#pragma unroll
    for (int k = 24; k < 32; ++k) h[k] = (_Float16)0.0f;

    const vf4* hv = (const vf4*)h;
    vf4* dst = lut8 + (size_t)i * 4;
    dst[0] = hv[0];
    dst[1] = hv[1];
    dst[2] = hv[2];
    dst[3] = hv[3];
}

__device__ __forceinline__ void trilerp8(
        float r, float g, float b, const vf4* __restrict__ lut8,
        float& o0, float& o1, float& o2) {
    float rs = fminf(fmaxf(r, 0.0f), 1.0f) * 32.0f;
    float gs = fminf(fmaxf(g, 0.0f), 1.0f) * 32.0f;
    float bs = fminf(fmaxf(b, 0.0f), 1.0f) * 32.0f;
    int ri = min((int)rs, 31);   // rs >= 0 so (int) == floor
    int gi = min((int)gs, 31);
    int bi = min((int)bs, 31);
    float fr = rs - (float)ri;
    float fg = gs - (float)gi;
    float fb = bs - (float)bi;

    const vf4* e = lut8 + (size_t)(bi * DIM2 + gi * DIM + ri) * 4;
    F4H q0, q1, q2;
    q0.f4 = e[0];
    q1.f4 = e[1];
    q2.f4 = e[2];

    float c[24];
#pragma unroll
    for (int j = 0; j < 8; ++j) {
        c[j]      = (float)q0.h[j];
        c[8 + j]  = (float)q1.h[j];
        c[16 + j] = (float)q2.h[j];
    }

    float wr[2] = {1.0f - fr, fr};
    float wg[2] = {1.0f - fg, fg};
    float wb[2] = {1.0f - fb, fb};
    float a0 = 0.0f, a1 = 0.0f, a2 = 0.0f;
#pragma unroll
    for (int db = 0; db < 2; ++db)
#pragma unroll
        for (int dg = 0; dg < 2; ++dg) {
            float wbg = wb[db] * wg[dg];
#pragma unroll
            for (int dr = 0; dr < 2; ++dr) {
                float w = wbg * wr[dr];
                int ci = ((db * 2 + dg) * 2 + dr) * 3;
                a0 = fmaf(w, c[ci + 0], a0);
                a1 = fmaf(w, c[ci + 1], a1);
                a2 = fmaf(w, c[ci + 2], a2);
            }
        }
    o0 = a0; o1 = a1; o2 = a2;
}

// Main kernel: 4 pixels/thread; non-temporal vf4 x-loads and out-stores so the
// streaming traffic doesn't evict LUT lines; 3 same-line dwordx4 gathers/pixel.
__global__ __launch_bounds__(256) void lut_apply_fp16x8(
        const float* __restrict__ x, const vf4* __restrict__ lut8,
        float* __restrict__ out) {
    int i4 = blockIdx.x * blockDim.x + threadIdx.x;
    const int HW4 = HW / 4;
    if (i4 >= NPIX / 4) return;
    int n   = i4 / HW4;
    int rem = i4 - n * HW4;
    size_t base = (size_t)n * (size_t)(3 * HW) + (size_t)rem * 4;

    const vf4 rv = __builtin_nontemporal_load((const vf4*)(x + base));
    const vf4 gv = __builtin_nontemporal_load((const vf4*)(x + base + HW));
    const vf4 bv = __builtin_nontemporal_load((const vf4*)(x + base + 2 * (size_t)HW));

    float oa[4], ob[4], oc[4];
#pragma unroll
    for (int k = 0; k < 4; ++k) {
        trilerp8(rv[k], gv[k], bv[k], lut8, oa[k], ob[k], oc[k]);
    }
    vf4 o0 = {oa[0], oa[1], oa[2], oa[3]};
    vf4 o1 = {ob[0], ob[1], ob[2], ob[3]};
    vf4 o2 = {oc[0], oc[1], oc[2], oc[3]};
    __builtin_nontemporal_store(o0, (vf4*)(out + base));
    __builtin_nontemporal_store(o1, (vf4*)(out + base + HW));
    __builtin_nontemporal_store(o2, (vf4*)(out + base + 2 * (size_t)HW));
}

extern "C" void kernel_launch(void* const* d_in, const int* in_sizes, int n_in,
                              void* d_out, int out_size, void* d_ws, size_t ws_size,
                              hipStream_t stream) {
    const float* x   = (const float*)d_in[0];
    const float* lut = (const float*)d_in[1];
    float* out = (float*)d_out;

    const int groups = NPIX / 4;              // 2,073,600 float4 pixel-groups
    const int blocks = (groups + 255) / 256;  // 8100

    vf4* lut8 = (vf4*)d_ws;                   // needs DIM3*64 = 2.3 MB of ws
    pack_lut8_kernel<<<(DIM3 + 255) / 256, 256, 0, stream>>>(lut, lut8);
    lut_apply_fp16x8<<<blocks, 256, 0, stream>>>(x, lut8, out);
}